// Round 2
// baseline (831.136 us; speedup 1.0000x reference)
//
#include <hip/hip_runtime.h>
#include <hip/hip_bf16.h>

#define DIN 128
#define HID 32
#define EPS 1e-5f
#define FXS 16777216.0f             // 2^24 fixed-point scale for deg accumulation
#define FXI 5.9604644775390625e-8f  // 2^-24

typedef unsigned int u32;
typedef unsigned short u16;
typedef unsigned long long u64;

// extract bf16 half of a packed u32 (hi=0 -> low 16 bits = even channel) as float
__device__ __forceinline__ float bfx(u32 v, int hi) {
    return __uint_as_float(hi ? (v & 0xffff0000u) : (v << 16));
}

__device__ __forceinline__ u16 f2bf(float f) {
    __hip_bfloat16 h = __float2bfloat16(f);
    return *reinterpret_cast<u16*>(&h);
}

// ---------------- init: zero per-XCD u64 count/deg replicas + BN stats ----------------
__global__ void init_cnt(u64* __restrict__ cnt, float* __restrict__ stats, int n8) {
    int i = blockIdx.x * blockDim.x + threadIdx.x;
    if (i < n8) cnt[i] = 0ull;
    if (i < 192) stats[i] = 0.f;
}

// ---------------- fused: per-XCD histogram/rank + layer-0 GEMM ----------------
// hist path: one u64 atomic per edge into the XCD-LOCAL replica (workgroup scope ->
// RMW retires in the local L2, never crosses the fabric). xcd-major layout: no cache
// line is ever shared across XCDs, so local-L2 atomicity is sufficient.
// rank packs (local_rank << 3) | xcd.
// gemm path: x fp32 @ W0 -> hbf bf16, split-major halves (identical to old gemm_din).
// Even/odd block interleave keeps both kinds co-resident so the GEMM's VALU/HBM work
// fills the pipes the atomic-bound hist blocks leave idle.
__global__ void hist_gemm(const int* __restrict__ col, const float* __restrict__ w,
                          u64* __restrict__ cnt, int* __restrict__ rank, int E,
                          const float* __restrict__ x, const float* __restrict__ W,
                          u16* __restrict__ hbf, int n, int egrid, int ngem) {
    __shared__ float Wl[DIN * HID];
    int bid = blockIdx.x;
    int mn = (egrid < ngem) ? egrid : ngem;
    bool isG;
    int idx;
    if (bid < 2 * mn) {
        isG = bid & 1;
        idx = bid >> 1;
    } else {
        isG = (ngem > egrid);
        idx = mn + (bid - 2 * mn);
    }
    if (isG) {
        for (int i = threadIdx.x; i < DIN * HID; i += blockDim.x) Wl[i] = W[i];
        __syncthreads();  // block-uniform path: every thread reaches this barrier
        int ch = threadIdx.x & 31;
        int node = idx * 8 + (threadIdx.x >> 5);
        if (node >= n) return;
        const float* xr = x + (size_t)node * DIN;
        float acc = 0.f;
#pragma unroll 8
        for (int k = 0; k < DIN; ++k) acc += xr[k] * Wl[k * HID + ch];
        hbf[(size_t)(ch >> 4) * n * 16 + node * 16 + (ch & 15)] = f2bf(acc);
    } else {
        int e = idx * 256 + threadIdx.x;
        if (e >= E) return;
        u32 xcc;
        asm("s_getreg_b32 %0, hwreg(HW_REG_XCC_ID, 0, 32)" : "=s"(xcc));
        xcc &= 7u;
        int c = col[e];
        u32 fx = (u32)(w[e] * FXS + 0.5f);
        u64 old = __hip_atomic_fetch_add(&cnt[(size_t)xcc * n + c],
                                         (1ull << 32) | (u64)fx,
                                         __ATOMIC_RELAXED, __HIP_MEMORY_SCOPE_WORKGROUP);
        rank[e] = (int)(((old >> 32) << 3) | xcc);
    }
}

// fold 8 replicas -> rowptr (pre-scan counts), dinv, per-XCD exclusive offsets
__global__ void finalize_deg(const u64* __restrict__ cnt, u32* __restrict__ off,
                             int* __restrict__ rowptr, float* __restrict__ dinv, int n) {
    int i = blockIdx.x * blockDim.x + threadIdx.x;
    if (i >= n) return;
    u32 run = 0;
    u64 fx = 0;
#pragma unroll
    for (int xc = 0; xc < 8; ++xc) {
        u64 v = cnt[(size_t)xc * n + i];
        off[(size_t)xc * n + i] = run;
        run += (u32)(v >> 32);
        fx += (u64)(u32)v;
    }
    rowptr[i] = (int)run;
    dinv[i] = rsqrtf(1.0f + (float)fx * FXI);  // +1 self loop
}

// ---------------- exclusive scan over rowptr[0..n) ----------------
__global__ void scan_blocks(int* __restrict__ data, int* __restrict__ bsum, int n) {
    __shared__ int s[256];
    int i = blockIdx.x * 256 + threadIdx.x;
    int v = (i < n) ? data[i] : 0;
    s[threadIdx.x] = v;
    __syncthreads();
    for (int off = 1; off < 256; off <<= 1) {
        int t = (threadIdx.x >= off) ? s[threadIdx.x - off] : 0;
        __syncthreads();
        s[threadIdx.x] += t;
        __syncthreads();
    }
    if (i < n) data[i] = s[threadIdx.x] - v;  // exclusive
    if (threadIdx.x == 255) bsum[blockIdx.x] = s[255];
}

__global__ void scan_tops(int* __restrict__ bsum, int nb) {
    __shared__ int s[512];
    int v = (threadIdx.x < nb) ? bsum[threadIdx.x] : 0;
    s[threadIdx.x] = v;
    __syncthreads();
    for (int off = 1; off < 512; off <<= 1) {
        int t = (threadIdx.x >= off) ? s[threadIdx.x - off] : 0;
        __syncthreads();
        s[threadIdx.x] += t;
        __syncthreads();
    }
    if (threadIdx.x < nb) bsum[threadIdx.x] = s[threadIdx.x] - v;  // exclusive
}

__global__ void scan_addback(int* __restrict__ data, const int* __restrict__ bsum,
                             int n, int E) {
    int i = blockIdx.x * 256 + threadIdx.x;
    if (i < n) data[i] += bsum[blockIdx.x];
    if (i == n) data[n] = E;  // sentinel end
}

// ---------------- atomic-free scatter into CSR, 4-byte packed entries ----------------
// entry = (src << 15) | bf16_bits(norm); norm >= 0 so bf16 sign bit = 0 (15 bits)
__global__ void scatter_pos(const int* __restrict__ row, const int* __restrict__ col,
                            const float* __restrict__ w, const float* __restrict__ dinv,
                            const int* __restrict__ rowptr, const int* __restrict__ rank,
                            const u32* __restrict__ off, u32* __restrict__ esort,
                            int E, int n) {
    int e = blockIdx.x * blockDim.x + threadIdx.x;
    if (e < E) {
        int r = row[e], c = col[e];
        float nv = dinv[r] * w[e] * dinv[c];
        int rv = rank[e];
        int pos = rowptr[c] + (int)off[(size_t)(rv & 7) * n + c] + (rv >> 3);
        esort[pos] = ((u32)r << 15) | (u32)f2bf(nv);
    }
}

// ---------------- hidden GEMM, fused BN+ReLU on input (split-major agg in/out) -------
__global__ void gemm_hid_bn(const float* __restrict__ aS, const float* __restrict__ W,
                            const float* __restrict__ stats, const float* __restrict__ g,
                            const float* __restrict__ be, u16* __restrict__ hbf,
                            int n, float invN) {
    __shared__ float Wl[HID * HID];
    __shared__ float sc[HID], sh[HID];
    int t = threadIdx.x;
    for (int i = t; i < HID * HID; i += blockDim.x) Wl[i] = W[i];
    if (t < HID) {
        float mu = stats[t] * invN;
        float var = stats[32 + t] * invN - mu * mu;
        float s = rsqrtf(var + EPS) * g[t];
        sc[t] = s;
        sh[t] = be[t] - mu * s;
    }
    __syncthreads();
    int ch = t & 31;
    int node = blockIdx.x * 8 + (t >> 5);
    if (node >= n) return;
    float acc = 0.f;
#pragma unroll
    for (int k = 0; k < HID; ++k) {
        float av = aS[(size_t)(k >> 4) * n * 16 + node * 16 + (k & 15)];
        float v = fmaxf(av * sc[k] + sh[k], 0.f);
        acc += v * Wl[k * HID + ch];
    }
    hbf[(size_t)(ch >> 4) * n * 16 + node * 16 + (ch & 15)] = f2bf(acc);
}

// ---------------- channel-half CSR gather ----------------
// h2 = this half's packed rows (8 u32/node, 32 B/row, 3.2 MB -> L2-resident).
// out = this half's OWN contiguous region (no cross-kernel line sharing):
// out[node*16 + c]. 16 lanes per node.
__global__ void gather_half(const u32* __restrict__ h2, const int* __restrict__ rowptr,
                            const u32* __restrict__ esort, const float* __restrict__ dinv,
                            const float* __restrict__ b, float* __restrict__ out,
                            int n, int half) {
    int c = threadIdx.x & 15;
    int node = blockIdx.x * 16 + (threadIdx.x >> 4);
    if (node >= n) return;
    int p = c >> 1, hi = c & 1;
    float dv = dinv[node];
    float acc = dv * dv * bfx(h2[node * 8 + p], hi) + b[half * 16 + c];
    int start = rowptr[node], end = rowptr[node + 1];
    int j = start;
    for (; j + 4 <= end; j += 4) {
        u32 e0 = esort[j];
        u32 e1 = esort[j + 1];
        u32 e2 = esort[j + 2];
        u32 e3 = esort[j + 3];
        u32 v0 = h2[(e0 >> 15) * 8 + p];
        u32 v1 = h2[(e1 >> 15) * 8 + p];
        u32 v2 = h2[(e2 >> 15) * 8 + p];
        u32 v3 = h2[(e3 >> 15) * 8 + p];
        acc += __uint_as_float((e0 & 0x7fffu) << 16) * bfx(v0, hi);
        acc += __uint_as_float((e1 & 0x7fffu) << 16) * bfx(v1, hi);
        acc += __uint_as_float((e2 & 0x7fffu) << 16) * bfx(v2, hi);
        acc += __uint_as_float((e3 & 0x7fffu) << 16) * bfx(v3, hi);
    }
    for (; j < end; ++j) {
        u32 ed = esort[j];
        acc += __uint_as_float((ed & 0x7fffu) << 16) * bfx(h2[(ed >> 15) * 8 + p], hi);
    }
    out[node * 16 + c] = acc;
}

// ---------------- BN stats reduce (split-major agg) ----------------
__global__ void bn_reduce(const float* __restrict__ aS, float* __restrict__ stats, int n) {
    __shared__ float s1[256], s2[256];
    int ch = threadIdx.x & 31, rg = threadIdx.x >> 5;
    size_t base = (size_t)(ch >> 4) * n * 16 + (ch & 15);
    float a = 0.f, b = 0.f;
    for (int node = blockIdx.x * 8 + rg; node < n; node += gridDim.x * 8) {
        float v = aS[base + node * 16];
        a += v;
        b += v * v;
    }
    s1[threadIdx.x] = a;
    s2[threadIdx.x] = b;
    __syncthreads();
    if (threadIdx.x < 32) {
        float ta = 0.f, tb = 0.f;
#pragma unroll
        for (int j = 0; j < 8; ++j) {
            ta += s1[j * 32 + threadIdx.x];
            tb += s2[j * 32 + threadIdx.x];
        }
        atomicAdd(&stats[threadIdx.x], ta);
        atomicAdd(&stats[32 + threadIdx.x], tb);
    }
}

// ---------------- final merge: split-major agg -> node-major d_out with ReLU --------
__global__ void merge_relu(const float* __restrict__ aS, float* __restrict__ out, int n) {
    int gid = blockIdx.x * blockDim.x + threadIdx.x;
    if (gid >= n * HID) return;
    int node = gid >> 5, ch = gid & 31;
    float v = aS[(size_t)(ch >> 4) * n * 16 + node * 16 + (ch & 15)];
    out[gid] = fmaxf(v, 0.f);
}

extern "C" void kernel_launch(void* const* d_in, const int* in_sizes, int n_in,
                              void* d_out, int out_size, void* d_ws, size_t ws_size,
                              hipStream_t stream) {
    const int N = in_sizes[0] / DIN;
    const int E = in_sizes[2];

    const float* x = (const float*)d_in[0];
    const int* ei = (const int*)d_in[1];
    const float* ew = (const float*)d_in[2];
    const int* row = ei;
    const int* col = ei + E;

    const float* Ws[4] = {(const float*)d_in[3], (const float*)d_in[5],
                          (const float*)d_in[7], (const float*)d_in[9]};
    const float* bs[4] = {(const float*)d_in[4], (const float*)d_in[6],
                          (const float*)d_in[8], (const float*)d_in[10]};
    const float* gs[3] = {(const float*)d_in[11], (const float*)d_in[13], (const float*)d_in[15]};
    const float* bes[3] = {(const float*)d_in[12], (const float*)d_in[14], (const float*)d_in[16]};

    // workspace layout, every buffer 256B-aligned (~33 MB total)
    char* wsb = (char*)d_ws;
    size_t off0 = 0;
    auto alloc = [&](size_t bytes) -> void* {
        off0 = (off0 + 255) & ~(size_t)255;
        void* p = wsb + off0;
        off0 += bytes;
        return p;
    };
    float* dinv = (float*)alloc((size_t)N * 4);
    int* rowptr = (int*)alloc((size_t)(N + 1) * 4);
    u32* esort = (u32*)alloc((size_t)E * 4);
    u16* hbf = (u16*)alloc((size_t)N * HID * 2);       // bf16, split-major halves
    float* aggS = (float*)alloc((size_t)N * HID * 4);  // f32, split-major halves
    float* stats = (float*)alloc(192 * 4);
    int* bsum = (int*)alloc(512 * 4);
    int* rank = (int*)aggS;  // E ints alias aggS: rank dead before aggS first written

    // per-XCD counter replicas (8N u64 = 6.4MB) + offsets (8N u32 = 3.2MB) live in
    // d_out as scratch (12.8MB): both dead before merge_relu overwrites d_out.
    u64* cnt = (u64*)d_out;
    u32* xoff = (u32*)((char*)d_out + (size_t)N * 8 * sizeof(u64));

    const int B = 256;
    const int ngrid = (N + B - 1) / B;
    const int egrid = (E + B - 1) / B;
    const int ngem = (N + 7) / 8;
    const int nodeGrid16 = (N + 15) / 16;
    const int ngrid32 = (N * HID + B - 1) / B;
    const int scanBlocks = (N + 255) / 256;  // 391 <= 512
    const int cgrid = (N * 8 + B - 1) / B;
    const float invN = 1.0f / (float)N;

    // ---- build CSR + norm (layer-0 GEMM fused into the histogram launch) ----
    init_cnt<<<cgrid, B, 0, stream>>>(cnt, stats, N * 8);
    hist_gemm<<<egrid + ngem, B, 0, stream>>>(col, ew, cnt, rank, E,
                                              x, Ws[0], hbf, N, egrid, ngem);
    finalize_deg<<<ngrid, B, 0, stream>>>(cnt, xoff, rowptr, dinv, N);
    scan_blocks<<<scanBlocks, 256, 0, stream>>>(rowptr, bsum, N);
    scan_tops<<<1, 512, 0, stream>>>(bsum, scanBlocks);
    scan_addback<<<scanBlocks + 1, 256, 0, stream>>>(rowptr, bsum, N, E);
    scatter_pos<<<egrid, B, 0, stream>>>(row, col, ew, dinv, rowptr, rank, xoff, esort, E, N);

    // ---- layers ----
    for (int l = 0; l < 4; ++l) {
        if (l > 0)
            gemm_hid_bn<<<ngem, B, 0, stream>>>(aggS, Ws[l], stats + 64 * (l - 1),
                                                gs[l - 1], bes[l - 1], hbf, N, invN);

        // two channel-half passes; each touches only its 3.2 MB h-half and writes
        // its own contiguous 6.4 MB agg region (no cross-kernel line sharing)
        gather_half<<<nodeGrid16, B, 0, stream>>>((const u32*)hbf, rowptr, esort, dinv,
                                                  bs[l], aggS, N, 0);
        gather_half<<<nodeGrid16, B, 0, stream>>>((const u32*)(hbf + (size_t)N * 16),
                                                  rowptr, esort, dinv, bs[l],
                                                  aggS + (size_t)N * 16, N, 1);

        if (l < 3)
            bn_reduce<<<512, B, 0, stream>>>(aggS, stats + 64 * l, N);
        else
            merge_relu<<<ngrid32, B, 0, stream>>>(aggS, (float*)d_out, N);
    }
}

// Round 3
// 813.883 us; speedup vs baseline: 1.0212x; 1.0212x over previous
//
#include <hip/hip_runtime.h>
#include <hip/hip_bf16.h>

#define DIN 128
#define HID 32
#define EPS 1e-5f
#define BINS 16384        // bins per range-pass (LDS: 2 x 64KB arrays)
#define CHK 32            // edge chunks (blocks per range)
#define WSC 16384.0f      // 2^14 fixed-point scale for per-chunk w sums
#define WSI 6.103515625e-5f  // 2^-14

typedef unsigned int u32;
typedef unsigned short u16;
typedef unsigned long long u64;

// extract bf16 half of a packed u32 (hi=0 -> low 16 bits = even channel) as float
__device__ __forceinline__ float bfx(u32 v, int hi) {
    return __uint_as_float(hi ? (v & 0xffff0000u) : (v << 16));
}

__device__ __forceinline__ u16 f2bf(float f) {
    __hip_bfloat16 h = __float2bfloat16(f);
    return *reinterpret_cast<u16*>(&h);
}

// ---------------- zero BN stats ----------------
__global__ void init_stats(float* __restrict__ stats) {
    if (threadIdx.x < 192) stats[threadIdx.x] = 0.f;
}

// ---------------- counting-sort phase 1: per-(range,chunk) LDS histograms ----------
// block (r,c): LDS-histogram cols in [r*BINS,(r+1)*BINS) over edge chunk c.
// No global atomics. Writes partial counts + fixed-point w-sums, layout [c][r*BINS+b]
// (c-major so the scatter pass reads its column as one contiguous 64KB block).
__global__ __launch_bounds__(1024) void hist_part(
        const int* __restrict__ col, const float* __restrict__ w, int E, int R,
        u32* __restrict__ cpart, u32* __restrict__ wpart) {
    __shared__ u32 cnt[BINS];
    __shared__ u32 wfx[BINS];
    int r = blockIdx.x / CHK, c = blockIdx.x % CHK;
    for (int i = threadIdx.x; i < BINS; i += 1024) { cnt[i] = 0; wfx[i] = 0; }
    __syncthreads();
    int lo = r * BINS;
    int chunk = (E + CHK - 1) / CHK;
    int e0 = c * chunk;
    int e1 = e0 + chunk; if (e1 > E) e1 = E;
    for (int e = e0 + threadIdx.x; e < e1; e += 1024) {
        int b = col[e] - lo;
        if ((u32)b < (u32)BINS) {
            atomicAdd(&cnt[b], 1u);
            atomicAdd(&wfx[b], (u32)(w[e] * WSC + 0.5f));
        }
    }
    __syncthreads();
    size_t base = (size_t)c * ((size_t)R * BINS) + (size_t)r * BINS;
    for (int i = threadIdx.x; i < BINS; i += 1024) {
        cpart[base + i] = cnt[i];
        wpart[base + i] = wfx[i];
    }
}

// ---------------- phase 2: per-bin prefix over chunks + counts + dinv ----------------
// thread rb: cpart[c][rb] -> exclusive running prefix over c; total -> rowptr counts;
// w totals -> dinv (exact f32 deg from 2^-14 fixed point, +1 self loop).
__global__ void prefix_part(u32* __restrict__ cpart, const u32* __restrict__ wpart,
                            int* __restrict__ rowptr, float* __restrict__ dinv,
                            int N, int R) {
    int rb = blockIdx.x * 256 + threadIdx.x;
    int RB = R * BINS;
    if (rb >= RB) return;
    u32 run = 0;
    u64 wsum = 0;
    for (int c = 0; c < CHK; ++c) {
        size_t idx = (size_t)c * RB + rb;
        u32 cv = cpart[idx];
        cpart[idx] = run;
        run += cv;
        wsum += wpart[idx];
    }
    if (rb < N) {
        rowptr[rb] = (int)run;
        dinv[rb] = rsqrtf(1.0f + (float)wsum * WSI);
    }
}

// ---------------- exclusive scan over rowptr[0..n) ----------------
__global__ void scan_blocks(int* __restrict__ data, int* __restrict__ bsum, int n) {
    __shared__ int s[256];
    int i = blockIdx.x * 256 + threadIdx.x;
    int v = (i < n) ? data[i] : 0;
    s[threadIdx.x] = v;
    __syncthreads();
    for (int off = 1; off < 256; off <<= 1) {
        int t = (threadIdx.x >= off) ? s[threadIdx.x - off] : 0;
        __syncthreads();
        s[threadIdx.x] += t;
        __syncthreads();
    }
    if (i < n) data[i] = s[threadIdx.x] - v;  // exclusive
    if (threadIdx.x == 255) bsum[blockIdx.x] = s[255];
}

__global__ void scan_tops(int* __restrict__ bsum, int nb) {
    __shared__ int s[512];
    int v = (threadIdx.x < nb) ? bsum[threadIdx.x] : 0;
    s[threadIdx.x] = v;
    __syncthreads();
    for (int off = 1; off < 512; off <<= 1) {
        int t = (threadIdx.x >= off) ? s[threadIdx.x - off] : 0;
        __syncthreads();
        s[threadIdx.x] += t;
        __syncthreads();
    }
    if (threadIdx.x < nb) bsum[threadIdx.x] = s[threadIdx.x] - v;  // exclusive
}

__global__ void scan_addback(int* __restrict__ data, const int* __restrict__ bsum,
                             int n, int E) {
    int i = blockIdx.x * 256 + threadIdx.x;
    if (i < n) data[i] += bsum[blockIdx.x];
    if (i == n) data[n] = E;  // sentinel end
}

// ---------------- phase 3: atomic-free scatter into CSR (4-byte packed entries) -----
// block (r,c): re-histogram chunk c locally (LDS atomic -> local rank), slot =
// rowptr[col] + chunk-prefix + rank. norm computed inline (dinv ready).
// entry = (src << 15) | bf16_bits(norm); norm >= 0 so bf16 sign bit = 0.
__global__ __launch_bounds__(1024) void scatter_sort(
        const int* __restrict__ row, const int* __restrict__ col,
        const float* __restrict__ w, const float* __restrict__ dinv,
        const int* __restrict__ rowptr, const u32* __restrict__ cpart,
        u32* __restrict__ esort, int E, int R) {
    __shared__ u32 cnt[BINS];
    __shared__ u32 basep[BINS];
    int r = blockIdx.x / CHK, c = blockIdx.x % CHK;
    size_t pb = (size_t)c * ((size_t)R * BINS) + (size_t)r * BINS;
    for (int i = threadIdx.x; i < BINS; i += 1024) {
        cnt[i] = 0;
        basep[i] = cpart[pb + i];
    }
    __syncthreads();
    int lo = r * BINS;
    int chunk = (E + CHK - 1) / CHK;
    int e0 = c * chunk;
    int e1 = e0 + chunk; if (e1 > E) e1 = E;
    for (int e = e0 + threadIdx.x; e < e1; e += 1024) {
        int cc = col[e];
        int b = cc - lo;
        if ((u32)b < (u32)BINS) {
            u32 rk = atomicAdd(&cnt[b], 1u);
            int src = row[e];
            float nv = dinv[src] * w[e] * dinv[cc];
            int pos = rowptr[cc] + (int)basep[b] + (int)rk;
            esort[pos] = ((u32)src << 15) | (u32)f2bf(nv);
        }
    }
}

// ---------------- layer-0 GEMM (x fp32 -> h bf16, split-major halves) ----------------
// LDS-staged: 64 node-rows of x loaded coalesced (float4), then 8 outputs/thread.
__global__ __launch_bounds__(256) void gemm_din(const float* __restrict__ x,
                                                const float* __restrict__ W,
                                                u16* __restrict__ hbf, int n) {
    __shared__ float xl[64][DIN];     // 32KB; xl[nn][k]: 2-way bank alias only (free)
    __shared__ float Wl[DIN * HID];   // 16KB
    int t = threadIdx.x;
    for (int i = t; i < DIN * HID; i += 256) Wl[i] = W[i];
    int nbase = blockIdx.x * 64;
    int nrows = n - nbase; if (nrows > 64) nrows = 64;
    const float4* xv = (const float4*)(x + (size_t)nbase * DIN);
    float4* xlv = (float4*)&xl[0][0];
    int f4cnt = nrows * (DIN / 4);
    for (int i = t; i < f4cnt; i += 256) xlv[i] = xv[i];
    __syncthreads();
    int ch = t & 31, ng = t >> 5;
    for (int nn = ng; nn < nrows; nn += 8) {
        float a0 = 0.f, a1 = 0.f, a2 = 0.f, a3 = 0.f;
#pragma unroll 8
        for (int k = 0; k < DIN; k += 4) {
            a0 += xl[nn][k + 0] * Wl[(k + 0) * HID + ch];
            a1 += xl[nn][k + 1] * Wl[(k + 1) * HID + ch];
            a2 += xl[nn][k + 2] * Wl[(k + 2) * HID + ch];
            a3 += xl[nn][k + 3] * Wl[(k + 3) * HID + ch];
        }
        int node = nbase + nn;
        hbf[(size_t)(ch >> 4) * n * 16 + node * 16 + (ch & 15)] = f2bf((a0 + a1) + (a2 + a3));
    }
}

// ---------------- hidden GEMM, fused BN+ReLU on input (split-major agg in/out) -------
__global__ void gemm_hid_bn(const float* __restrict__ aS, const float* __restrict__ W,
                            const float* __restrict__ stats, const float* __restrict__ g,
                            const float* __restrict__ be, u16* __restrict__ hbf,
                            int n, float invN) {
    __shared__ float Wl[HID * HID];
    __shared__ float sc[HID], sh[HID];
    int t = threadIdx.x;
    for (int i = t; i < HID * HID; i += blockDim.x) Wl[i] = W[i];
    if (t < HID) {
        float mu = stats[t] * invN;
        float var = stats[32 + t] * invN - mu * mu;
        float s = rsqrtf(var + EPS) * g[t];
        sc[t] = s;
        sh[t] = be[t] - mu * s;
    }
    __syncthreads();
    int ch = t & 31;
    int node = blockIdx.x * 8 + (t >> 5);
    if (node >= n) return;
    float acc = 0.f;
#pragma unroll
    for (int k = 0; k < HID; ++k) {
        float av = aS[(size_t)(k >> 4) * n * 16 + node * 16 + (k & 15)];
        float v = fmaxf(av * sc[k] + sh[k], 0.f);
        acc += v * Wl[k * HID + ch];
    }
    hbf[(size_t)(ch >> 4) * n * 16 + node * 16 + (ch & 15)] = f2bf(acc);
}

// ---------------- channel-half CSR gather ----------------
__global__ void gather_half(const u32* __restrict__ h2, const int* __restrict__ rowptr,
                            const u32* __restrict__ esort, const float* __restrict__ dinv,
                            const float* __restrict__ b, float* __restrict__ out,
                            int n, int half) {
    int c = threadIdx.x & 15;
    int node = blockIdx.x * 16 + (threadIdx.x >> 4);
    if (node >= n) return;
    int p = c >> 1, hi = c & 1;
    float dv = dinv[node];
    float acc = dv * dv * bfx(h2[node * 8 + p], hi) + b[half * 16 + c];
    int start = rowptr[node], end = rowptr[node + 1];
    int j = start;
    for (; j + 4 <= end; j += 4) {
        u32 e0 = esort[j];
        u32 e1 = esort[j + 1];
        u32 e2 = esort[j + 2];
        u32 e3 = esort[j + 3];
        u32 v0 = h2[(e0 >> 15) * 8 + p];
        u32 v1 = h2[(e1 >> 15) * 8 + p];
        u32 v2 = h2[(e2 >> 15) * 8 + p];
        u32 v3 = h2[(e3 >> 15) * 8 + p];
        acc += __uint_as_float((e0 & 0x7fffu) << 16) * bfx(v0, hi);
        acc += __uint_as_float((e1 & 0x7fffu) << 16) * bfx(v1, hi);
        acc += __uint_as_float((e2 & 0x7fffu) << 16) * bfx(v2, hi);
        acc += __uint_as_float((e3 & 0x7fffu) << 16) * bfx(v3, hi);
    }
    for (; j < end; ++j) {
        u32 ed = esort[j];
        acc += __uint_as_float((ed & 0x7fffu) << 16) * bfx(h2[(ed >> 15) * 8 + p], hi);
    }
    out[node * 16 + c] = acc;
}

// ---------------- BN stats reduce (split-major agg) ----------------
__global__ void bn_reduce(const float* __restrict__ aS, float* __restrict__ stats, int n) {
    __shared__ float s1[256], s2[256];
    int ch = threadIdx.x & 31, rg = threadIdx.x >> 5;
    size_t base = (size_t)(ch >> 4) * n * 16 + (ch & 15);
    float a = 0.f, b = 0.f;
    for (int node = blockIdx.x * 8 + rg; node < n; node += gridDim.x * 8) {
        float v = aS[base + node * 16];
        a += v;
        b += v * v;
    }
    s1[threadIdx.x] = a;
    s2[threadIdx.x] = b;
    __syncthreads();
    if (threadIdx.x < 32) {
        float ta = 0.f, tb = 0.f;
#pragma unroll
        for (int j = 0; j < 8; ++j) {
            ta += s1[j * 32 + threadIdx.x];
            tb += s2[j * 32 + threadIdx.x];
        }
        atomicAdd(&stats[threadIdx.x], ta);
        atomicAdd(&stats[32 + threadIdx.x], tb);
    }
}

// ---------------- final merge: split-major agg -> node-major d_out with ReLU --------
__global__ void merge_relu(const float* __restrict__ aS, float* __restrict__ out, int n) {
    int gid = blockIdx.x * blockDim.x + threadIdx.x;
    if (gid >= n * HID) return;
    int node = gid >> 5, ch = gid & 31;
    float v = aS[(size_t)(ch >> 4) * n * 16 + node * 16 + (ch & 15)];
    out[gid] = fmaxf(v, 0.f);
}

extern "C" void kernel_launch(void* const* d_in, const int* in_sizes, int n_in,
                              void* d_out, int out_size, void* d_ws, size_t ws_size,
                              hipStream_t stream) {
    const int N = in_sizes[0] / DIN;
    const int E = in_sizes[2];
    const int R = (N + BINS - 1) / BINS;  // ranges (7 for N=100000)

    const float* x = (const float*)d_in[0];
    const int* ei = (const int*)d_in[1];
    const float* ew = (const float*)d_in[2];
    const int* row = ei;
    const int* col = ei + E;

    const float* Ws[4] = {(const float*)d_in[3], (const float*)d_in[5],
                          (const float*)d_in[7], (const float*)d_in[9]};
    const float* bs[4] = {(const float*)d_in[4], (const float*)d_in[6],
                          (const float*)d_in[8], (const float*)d_in[10]};
    const float* gs[3] = {(const float*)d_in[11], (const float*)d_in[13], (const float*)d_in[15]};
    const float* bes[3] = {(const float*)d_in[12], (const float*)d_in[14], (const float*)d_in[16]};

    // workspace layout, every buffer 256B-aligned (~35 MB total)
    char* wsb = (char*)d_ws;
    size_t off0 = 0;
    auto alloc = [&](size_t bytes) -> void* {
        off0 = (off0 + 255) & ~(size_t)255;
        void* p = wsb + off0;
        off0 += bytes;
        return p;
    };
    const size_t partBytes = (size_t)R * BINS * CHK * 4;  // 14.7 MB at N=100K

    float* dinv = (float*)alloc((size_t)N * 4);
    int* rowptr = (int*)alloc((size_t)(N + 1) * 4);
    // esort (E*4) and hbf (N*HID*2) allocated as ONE region so wpart can alias both:
    // wpart dead after prefix_part; esort first written in scatter_sort, hbf first
    // written by gemm_din which is launched AFTER prefix_part.
    u32* esort = (u32*)alloc((size_t)E * 4 + (size_t)N * HID * 2);
    u16* hbf = (u16*)(esort + E);
    // aggS region sized to also hold cpart: cpart dead after scatter_sort; aggS first
    // written by the layer-0 gathers, which run after scatter_sort.
    size_t aggBytes = (size_t)N * HID * 4;
    float* aggS = (float*)alloc(aggBytes > partBytes ? aggBytes : partBytes);
    float* stats = (float*)alloc(192 * 4);
    int* bsum = (int*)alloc(512 * 4);
    u32* cpart = (u32*)aggS;
    u32* wpart = (u32*)esort;

    const int B = 256;
    const int nodeGrid16 = (N + 15) / 16;
    const int ngrid32 = (N * HID + B - 1) / B;
    const int scanBlocks = (N + 255) / 256;  // 391 <= 512
    const int sortGrid = R * CHK;            // 224
    const int prefGrid = (R * BINS + 255) / 256;
    const float invN = 1.0f / (float)N;

    // ---- build CSR + norm: atomic-free counting sort ----
    init_stats<<<1, 256, 0, stream>>>(stats);
    hist_part<<<sortGrid, 1024, 0, stream>>>(col, ew, E, R, cpart, wpart);
    prefix_part<<<prefGrid, 256, 0, stream>>>(cpart, wpart, rowptr, dinv, N, R);
    gemm_din<<<(N + 63) / 64, 256, 0, stream>>>(x, Ws[0], hbf, N);  // frees wpart alias
    scan_blocks<<<scanBlocks, 256, 0, stream>>>(rowptr, bsum, N);
    scan_tops<<<1, 512, 0, stream>>>(bsum, scanBlocks);
    scan_addback<<<scanBlocks + 1, 256, 0, stream>>>(rowptr, bsum, N, E);
    scatter_sort<<<sortGrid, 1024, 0, stream>>>(row, col, ew, dinv, rowptr, cpart,
                                                esort, E, R);

    // ---- layers ----
    for (int l = 0; l < 4; ++l) {
        if (l > 0)
            gemm_hid_bn<<<(N + 7) / 8, B, 0, stream>>>(aggS, Ws[l], stats + 64 * (l - 1),
                                                       gs[l - 1], bes[l - 1], hbf, N, invN);

        // two channel-half passes; each touches only its 3.2 MB h-half and writes
        // its own contiguous 6.4 MB agg region (no cross-kernel line sharing)
        gather_half<<<nodeGrid16, B, 0, stream>>>((const u32*)hbf, rowptr, esort, dinv,
                                                  bs[l], aggS, N, 0);
        gather_half<<<nodeGrid16, B, 0, stream>>>((const u32*)(hbf + (size_t)N * 16),
                                                  rowptr, esort, dinv, bs[l],
                                                  aggS + (size_t)N * 16, N, 1);

        if (l < 3)
            bn_reduce<<<512, B, 0, stream>>>(aggS, stats + 64 * l, N);
        else
            merge_relu<<<ngrid32, B, 0, stream>>>(aggS, (float*)d_out, N);
    }
}

// Round 4
// 787.870 us; speedup vs baseline: 1.0549x; 1.0330x over previous
//
#include <hip/hip_runtime.h>
#include <hip/hip_bf16.h>

#define DIN 128
#define HID 32
#define EPS 1e-5f
#define BINS 16384        // bins per range-pass (LDS: 128KB)
#define CHK 32            // edge chunks (blocks per range)
#define NXCD 8
#define WSC 16384.0f      // 2^14 fixed-point scale for per-chunk w sums
#define WSI 6.103515625e-5f  // 2^-14

typedef unsigned int u32;
typedef unsigned short u16;
typedef unsigned long long u64;

// extract bf16 half of a packed u32 (hi=0 -> low 16 bits = even channel) as float
__device__ __forceinline__ float bfx(u32 v, int hi) {
    return __uint_as_float(hi ? (v & 0xffff0000u) : (v << 16));
}

__device__ __forceinline__ u16 f2bf(float f) {
    __hip_bfloat16 h = __float2bfloat16(f);
    return *reinterpret_cast<u16*>(&h);
}

// ---------------- zero BN stats ----------------
__global__ void init_stats(float* __restrict__ stats) {
    if (threadIdx.x < 192) stats[threadIdx.x] = 0.f;
}

// ---------------- counting-sort phase 1: per-(range,chunk) LDS histograms ----------
// bid = c*8 + r so all blocks of range r land on XCD r (round-robin dispatch);
// single u64 LDS atomic per in-range edge: count in hi32, fixed-point w in lo32.
__global__ __launch_bounds__(1024) void hist_part(
        const int* __restrict__ col, const float* __restrict__ w, int E, int R,
        u32* __restrict__ cpart, u32* __restrict__ wpart) {
    __shared__ u64 cw[BINS];  // 128KB
    int r = blockIdx.x & (NXCD - 1), c = blockIdx.x >> 3;
    if (r >= R) return;
    for (int i = threadIdx.x; i < BINS; i += 1024) cw[i] = 0ull;
    __syncthreads();
    int lo = r * BINS;
    int chunk = (E + CHK - 1) / CHK;
    int e0 = c * chunk;
    int e1 = e0 + chunk; if (e1 > E) e1 = E;
    for (int e = e0 + threadIdx.x; e < e1; e += 1024) {
        int b = col[e] - lo;
        if ((u32)b < (u32)BINS) {
            u64 add = (1ull << 32) | (u64)(u32)(w[e] * WSC + 0.5f);
            atomicAdd(&cw[b], add);
        }
    }
    __syncthreads();
    size_t base = (size_t)c * ((size_t)R * BINS) + (size_t)r * BINS;
    for (int i = threadIdx.x; i < BINS; i += 1024) {
        u64 v = cw[i];
        cpart[base + i] = (u32)(v >> 32);
        wpart[base + i] = (u32)v;
    }
}

// ---------------- phase 2: per-bin prefix over chunks + counts + dinv ----------------
__global__ void prefix_part(u32* __restrict__ cpart, const u32* __restrict__ wpart,
                            int* __restrict__ rowptr, float* __restrict__ dinv,
                            int N, int R) {
    int rb = blockIdx.x * 256 + threadIdx.x;
    int RB = R * BINS;
    if (rb >= RB) return;
    u32 run = 0;
    u64 wsum = 0;
    for (int c = 0; c < CHK; ++c) {
        size_t idx = (size_t)c * RB + rb;
        u32 cv = cpart[idx];
        cpart[idx] = run;
        run += cv;
        wsum += wpart[idx];
    }
    if (rb < N) {
        rowptr[rb] = (int)run;
        dinv[rb] = rsqrtf(1.0f + (float)wsum * WSI);
    }
}

// ---------------- exclusive scan over rowptr[0..n) ----------------
__global__ void scan_blocks(int* __restrict__ data, int* __restrict__ bsum, int n) {
    __shared__ int s[256];
    int i = blockIdx.x * 256 + threadIdx.x;
    int v = (i < n) ? data[i] : 0;
    s[threadIdx.x] = v;
    __syncthreads();
    for (int off = 1; off < 256; off <<= 1) {
        int t = (threadIdx.x >= off) ? s[threadIdx.x - off] : 0;
        __syncthreads();
        s[threadIdx.x] += t;
        __syncthreads();
    }
    if (i < n) data[i] = s[threadIdx.x] - v;  // exclusive
    if (threadIdx.x == 255) bsum[blockIdx.x] = s[255];
}

__global__ void scan_tops(int* __restrict__ bsum, int nb) {
    __shared__ int s[512];
    int v = (threadIdx.x < nb) ? bsum[threadIdx.x] : 0;
    s[threadIdx.x] = v;
    __syncthreads();
    for (int off = 1; off < 512; off <<= 1) {
        int t = (threadIdx.x >= off) ? s[threadIdx.x - off] : 0;
        __syncthreads();
        s[threadIdx.x] += t;
        __syncthreads();
    }
    if (threadIdx.x < nb) bsum[threadIdx.x] = s[threadIdx.x] - v;  // exclusive
}

__global__ void scan_addback(int* __restrict__ data, const int* __restrict__ bsum,
                             int n, int E) {
    int i = blockIdx.x * 256 + threadIdx.x;
    if (i < n) data[i] += bsum[blockIdx.x];
    if (i == n) data[n] = E;  // sentinel end
}

// ---------------- phase 3: atomic-free scatter into CSR (4-byte packed entries) -----
// bid = c*8 + r: all blocks of range r run on XCD r, so every scattered 4B store for
// range r's ~1.8MB esort segment lands in ONE L2 -> lines fill completely and write
// back once (no cross-XCD partial-line writebacks, no fabric transaction-rate wall).
// entry = (src << 15) | bf16_bits(norm); norm >= 0 so bf16 sign bit = 0.
__global__ __launch_bounds__(1024) void scatter_sort(
        const int* __restrict__ row, const int* __restrict__ col,
        const float* __restrict__ w, const float* __restrict__ dinv,
        const int* __restrict__ rowptr, const u32* __restrict__ cpart,
        u32* __restrict__ esort, int E, int R) {
    __shared__ u32 cnt[BINS];
    __shared__ u32 basep[BINS];
    int r = blockIdx.x & (NXCD - 1), c = blockIdx.x >> 3;
    if (r >= R) return;
    size_t pb = (size_t)c * ((size_t)R * BINS) + (size_t)r * BINS;
    for (int i = threadIdx.x; i < BINS; i += 1024) {
        cnt[i] = 0;
        basep[i] = cpart[pb + i];
    }
    __syncthreads();
    int lo = r * BINS;
    int chunk = (E + CHK - 1) / CHK;
    int e0 = c * chunk;
    int e1 = e0 + chunk; if (e1 > E) e1 = E;
    for (int e = e0 + threadIdx.x; e < e1; e += 1024) {
        int cc = col[e];
        int b = cc - lo;
        if ((u32)b < (u32)BINS) {
            u32 rk = atomicAdd(&cnt[b], 1u);
            int src = row[e];
            float nv = dinv[src] * w[e] * dinv[cc];
            int pos = rowptr[cc] + (int)basep[b] + (int)rk;
            esort[pos] = ((u32)src << 15) | (u32)f2bf(nv);
        }
    }
}

// ---------------- layer-0 GEMM (x fp32 -> h bf16, split-major halves) ----------------
// LDS-staged: 64 node-rows of x loaded coalesced (float4), then 8 outputs/thread.
__global__ __launch_bounds__(256) void gemm_din(const float* __restrict__ x,
                                                const float* __restrict__ W,
                                                u16* __restrict__ hbf, int n) {
    __shared__ float xl[64][DIN];     // 32KB; xl[nn][k]: 2-way bank alias only (free)
    __shared__ float Wl[DIN * HID];   // 16KB
    int t = threadIdx.x;
    for (int i = t; i < DIN * HID; i += 256) Wl[i] = W[i];
    int nbase = blockIdx.x * 64;
    int nrows = n - nbase; if (nrows > 64) nrows = 64;
    const float4* xv = (const float4*)(x + (size_t)nbase * DIN);
    float4* xlv = (float4*)&xl[0][0];
    int f4cnt = nrows * (DIN / 4);
    for (int i = t; i < f4cnt; i += 256) xlv[i] = xv[i];
    __syncthreads();
    int ch = t & 31, ng = t >> 5;
    for (int nn = ng; nn < nrows; nn += 8) {
        float a0 = 0.f, a1 = 0.f, a2 = 0.f, a3 = 0.f;
#pragma unroll 8
        for (int k = 0; k < DIN; k += 4) {
            a0 += xl[nn][k + 0] * Wl[(k + 0) * HID + ch];
            a1 += xl[nn][k + 1] * Wl[(k + 1) * HID + ch];
            a2 += xl[nn][k + 2] * Wl[(k + 2) * HID + ch];
            a3 += xl[nn][k + 3] * Wl[(k + 3) * HID + ch];
        }
        int node = nbase + nn;
        hbf[(size_t)(ch >> 4) * n * 16 + node * 16 + (ch & 15)] = f2bf((a0 + a1) + (a2 + a3));
    }
}

// ---------------- hidden GEMM, fused BN+ReLU on input (split-major agg in/out) -------
__global__ void gemm_hid_bn(const float* __restrict__ aS, const float* __restrict__ W,
                            const float* __restrict__ stats, const float* __restrict__ g,
                            const float* __restrict__ be, u16* __restrict__ hbf,
                            int n, float invN) {
    __shared__ float Wl[HID * HID];
    __shared__ float sc[HID], sh[HID];
    int t = threadIdx.x;
    for (int i = t; i < HID * HID; i += blockDim.x) Wl[i] = W[i];
    if (t < HID) {
        float mu = stats[t] * invN;
        float var = stats[32 + t] * invN - mu * mu;
        float s = rsqrtf(var + EPS) * g[t];
        sc[t] = s;
        sh[t] = be[t] - mu * s;
    }
    __syncthreads();
    int ch = t & 31;
    int node = blockIdx.x * 8 + (t >> 5);
    if (node >= n) return;
    float acc = 0.f;
#pragma unroll
    for (int k = 0; k < HID; ++k) {
        float av = aS[(size_t)(k >> 4) * n * 16 + node * 16 + (k & 15)];
        float v = fmaxf(av * sc[k] + sh[k], 0.f);
        acc += v * Wl[k * HID + ch];
    }
    hbf[(size_t)(ch >> 4) * n * 16 + node * 16 + (ch & 15)] = f2bf(acc);
}

// ---------------- channel-half CSR gather ----------------
__global__ void gather_half(const u32* __restrict__ h2, const int* __restrict__ rowptr,
                            const u32* __restrict__ esort, const float* __restrict__ dinv,
                            const float* __restrict__ b, float* __restrict__ out,
                            int n, int half) {
    int c = threadIdx.x & 15;
    int node = blockIdx.x * 16 + (threadIdx.x >> 4);
    if (node >= n) return;
    int p = c >> 1, hi = c & 1;
    float dv = dinv[node];
    float acc = dv * dv * bfx(h2[node * 8 + p], hi) + b[half * 16 + c];
    int start = rowptr[node], end = rowptr[node + 1];
    int j = start;
    for (; j + 4 <= end; j += 4) {
        u32 e0 = esort[j];
        u32 e1 = esort[j + 1];
        u32 e2 = esort[j + 2];
        u32 e3 = esort[j + 3];
        u32 v0 = h2[(e0 >> 15) * 8 + p];
        u32 v1 = h2[(e1 >> 15) * 8 + p];
        u32 v2 = h2[(e2 >> 15) * 8 + p];
        u32 v3 = h2[(e3 >> 15) * 8 + p];
        acc += __uint_as_float((e0 & 0x7fffu) << 16) * bfx(v0, hi);
        acc += __uint_as_float((e1 & 0x7fffu) << 16) * bfx(v1, hi);
        acc += __uint_as_float((e2 & 0x7fffu) << 16) * bfx(v2, hi);
        acc += __uint_as_float((e3 & 0x7fffu) << 16) * bfx(v3, hi);
    }
    for (; j < end; ++j) {
        u32 ed = esort[j];
        acc += __uint_as_float((ed & 0x7fffu) << 16) * bfx(h2[(ed >> 15) * 8 + p], hi);
    }
    out[node * 16 + c] = acc;
}

// ---------------- BN stats reduce (split-major agg) ----------------
__global__ void bn_reduce(const float* __restrict__ aS, float* __restrict__ stats, int n) {
    __shared__ float s1[256], s2[256];
    int ch = threadIdx.x & 31, rg = threadIdx.x >> 5;
    size_t base = (size_t)(ch >> 4) * n * 16 + (ch & 15);
    float a = 0.f, b = 0.f;
    for (int node = blockIdx.x * 8 + rg; node < n; node += gridDim.x * 8) {
        float v = aS[base + node * 16];
        a += v;
        b += v * v;
    }
    s1[threadIdx.x] = a;
    s2[threadIdx.x] = b;
    __syncthreads();
    if (threadIdx.x < 32) {
        float ta = 0.f, tb = 0.f;
#pragma unroll
        for (int j = 0; j < 8; ++j) {
            ta += s1[j * 32 + threadIdx.x];
            tb += s2[j * 32 + threadIdx.x];
        }
        atomicAdd(&stats[threadIdx.x], ta);
        atomicAdd(&stats[32 + threadIdx.x], tb);
    }
}

// ---------------- final merge: split-major agg -> node-major d_out with ReLU --------
__global__ void merge_relu(const float* __restrict__ aS, float* __restrict__ out, int n) {
    int gid = blockIdx.x * blockDim.x + threadIdx.x;
    if (gid >= n * HID) return;
    int node = gid >> 5, ch = gid & 31;
    float v = aS[(size_t)(ch >> 4) * n * 16 + node * 16 + (ch & 15)];
    out[gid] = fmaxf(v, 0.f);
}

extern "C" void kernel_launch(void* const* d_in, const int* in_sizes, int n_in,
                              void* d_out, int out_size, void* d_ws, size_t ws_size,
                              hipStream_t stream) {
    const int N = in_sizes[0] / DIN;
    const int E = in_sizes[2];
    const int R = (N + BINS - 1) / BINS;  // ranges (7 for N=100000)

    const float* x = (const float*)d_in[0];
    const int* ei = (const int*)d_in[1];
    const float* ew = (const float*)d_in[2];
    const int* row = ei;
    const int* col = ei + E;

    const float* Ws[4] = {(const float*)d_in[3], (const float*)d_in[5],
                          (const float*)d_in[7], (const float*)d_in[9]};
    const float* bs[4] = {(const float*)d_in[4], (const float*)d_in[6],
                          (const float*)d_in[8], (const float*)d_in[10]};
    const float* gs[3] = {(const float*)d_in[11], (const float*)d_in[13], (const float*)d_in[15]};
    const float* bes[3] = {(const float*)d_in[12], (const float*)d_in[14], (const float*)d_in[16]};

    // workspace layout, every buffer 256B-aligned (~35 MB total)
    char* wsb = (char*)d_ws;
    size_t off0 = 0;
    auto alloc = [&](size_t bytes) -> void* {
        off0 = (off0 + 255) & ~(size_t)255;
        void* p = wsb + off0;
        off0 += bytes;
        return p;
    };
    const size_t partBytes = (size_t)R * BINS * CHK * 4;  // 14.7 MB at N=100K

    float* dinv = (float*)alloc((size_t)N * 4);
    int* rowptr = (int*)alloc((size_t)(N + 1) * 4);
    // esort (E*4) and hbf (N*HID*2) allocated as ONE region so wpart can alias both:
    // wpart dead after prefix_part; esort first written in scatter_sort, hbf first
    // written by gemm_din which is launched AFTER prefix_part.
    u32* esort = (u32*)alloc((size_t)E * 4 + (size_t)N * HID * 2);
    u16* hbf = (u16*)(esort + E);
    // aggS region sized to also hold cpart: cpart dead after scatter_sort; aggS first
    // written by the layer-0 gathers, which run after scatter_sort.
    size_t aggBytes = (size_t)N * HID * 4;
    float* aggS = (float*)alloc(aggBytes > partBytes ? aggBytes : partBytes);
    float* stats = (float*)alloc(192 * 4);
    int* bsum = (int*)alloc(512 * 4);
    u32* cpart = (u32*)aggS;
    u32* wpart = (u32*)esort;

    const int B = 256;
    const int nodeGrid16 = (N + 15) / 16;
    const int ngrid32 = (N * HID + B - 1) / B;
    const int scanBlocks = (N + 255) / 256;  // 391 <= 512
    const int sortGrid = NXCD * CHK;         // 256 = 1 block/CU; bid = c*8 + r
    const int prefGrid = (R * BINS + 255) / 256;
    const float invN = 1.0f / (float)N;

    // ---- build CSR + norm: atomic-free counting sort, XCD-pinned scatter ----
    init_stats<<<1, 256, 0, stream>>>(stats);
    hist_part<<<sortGrid, 1024, 0, stream>>>(col, ew, E, R, cpart, wpart);
    prefix_part<<<prefGrid, 256, 0, stream>>>(cpart, wpart, rowptr, dinv, N, R);
    gemm_din<<<(N + 63) / 64, 256, 0, stream>>>(x, Ws[0], hbf, N);  // frees wpart alias
    scan_blocks<<<scanBlocks, 256, 0, stream>>>(rowptr, bsum, N);
    scan_tops<<<1, 512, 0, stream>>>(bsum, scanBlocks);
    scan_addback<<<scanBlocks + 1, 256, 0, stream>>>(rowptr, bsum, N, E);
    scatter_sort<<<sortGrid, 1024, 0, stream>>>(row, col, ew, dinv, rowptr, cpart,
                                                esort, E, R);

    // ---- layers ----
    for (int l = 0; l < 4; ++l) {
        if (l > 0)
            gemm_hid_bn<<<(N + 7) / 8, B, 0, stream>>>(aggS, Ws[l], stats + 64 * (l - 1),
                                                       gs[l - 1], bes[l - 1], hbf, N, invN);

        // two channel-half passes; each touches only its 3.2 MB h-half and writes
        // its own contiguous 6.4 MB agg region (no cross-kernel line sharing)
        gather_half<<<nodeGrid16, B, 0, stream>>>((const u32*)hbf, rowptr, esort, dinv,
                                                  bs[l], aggS, N, 0);
        gather_half<<<nodeGrid16, B, 0, stream>>>((const u32*)(hbf + (size_t)N * 16),
                                                  rowptr, esort, dinv, bs[l],
                                                  aggS + (size_t)N * 16, N, 1);

        if (l < 3)
            bn_reduce<<<512, B, 0, stream>>>(aggS, stats + 64 * l, N);
        else
            merge_relu<<<ngrid32, B, 0, stream>>>(aggS, (float*)d_out, N);
    }
}